// Round 1
// baseline (484.689 us; speedup 1.0000x reference)
//
#include <hip/hip_runtime.h>

#define Bb 4
#define Ll 256
#define DN 256
#define DEg 128
#define Hh 8
#define DKk 32
#define DEe 16
#define NEG 0.2f

__device__ __forceinline__ float lrelu(float x) { return x >= 0.f ? x : NEG * x; }

// ---------------- prep: V (128x8), ch(8), c0(128) ----------------
__global__ void prep_small(const float* We_w, const float* We_b, const float* attn_w,
                           const float* We2_b, const float* edge_w, const float* edge_b,
                           const float* out_e_w, const float* out_e_b,
                           float* Vg, float* chg, float* c0g) {
  __shared__ float b2e[128];
  int t = threadIdx.x; // 128 threads
  const float* we = attn_w + 64;
  for (int idx = t; idx < 1024; idx += 128) {
    int c = idx >> 3, h = idx & 7;
    float s = 0.f;
    for (int d = 0; d < 16; ++d) s += We_w[c * 128 + h * 16 + d] * we[d];
    Vg[idx] = s; // V[c*8+h]
  }
  if (t < 8) {
    float s = 0.f;
    for (int d = 0; d < 16; ++d) s += We_b[t * 16 + d] * we[d];
    chg[t] = s;
  }
  {
    int h = t >> 4, e = t & 15;
    float s = 0.f;
    for (int d = 0; d < 16; ++d) s += We2_b[h * 16 + d] * edge_w[d * 16 + e];
    b2e[t] = s + edge_b[e];
  }
  __syncthreads();
  float s = out_e_b[t];
  for (int f = 0; f < 128; ++f) s += b2e[f] * out_e_w[f * 128 + t];
  c0g[t] = s;
}

// ---------------- prep: G = M2 @ out_e_w (128x128) ----------------
__global__ void prep_g(const float* We2_w, const float* edge_w, const float* out_e_w, float* Gg) {
  __shared__ float m2[128];
  int c = blockIdx.x, t = threadIdx.x; // 128 threads
  int h = t >> 4, e = t & 15;
  float s = 0.f;
  for (int d = 0; d < 16; ++d) s += We2_w[c * 128 + h * 16 + d] * edge_w[d * 16 + e];
  m2[t] = s;
  __syncthreads();
  float g = 0.f;
  for (int f = 0; f < 128; ++f) g += m2[f] * out_e_w[f * 128 + t];
  Gg[c * 128 + t] = g;
}

// ---------------- generic 256->256 row GEMM: out = A@W + b ----------------
template <int RPB>
__global__ __launch_bounds__(256) void rowgemm256(const float* A, const float* W,
                                                  const float* bias, float* out) {
  __shared__ float a[RPB][256];
  int t = threadIdx.x;
  int row0 = blockIdx.x * RPB;
  for (int q = t; q < RPB * 256; q += 256) a[q >> 8][q & 255] = A[(long)row0 * 256 + q];
  __syncthreads();
  float acc[RPB];
  float bv = bias[t];
#pragma unroll
  for (int r = 0; r < RPB; ++r) acc[r] = bv;
  for (int k = 0; k < 256; ++k) {
    float w = W[k * 256 + t];
#pragma unroll
    for (int r = 0; r < RPB; ++r) acc[r] += a[r][k] * w;
  }
#pragma unroll
  for (int r = 0; r < RPB; ++r) out[(long)(row0 + r) * 256 + t] = acc[r];
}

// ---------------- per-row head projections: Whh, si, sj ----------------
__global__ __launch_bounds__(256) void node_heads_kernel(const float* node_p, const float* Wh_w,
                                                         const float* Wh_b, const float* attn_w,
                                                         float* Whh, float* si, float* sj) {
  __shared__ float a[256];
  int row = blockIdx.x, t = threadIdx.x;
  a[t] = node_p[(long)row * 256 + t];
  __syncthreads();
  int h = t >> 5, e = t & 31;
  float acc = Wh_b[e];
  for (int d = 0; d < 32; ++d) acc += a[h * 32 + d] * Wh_w[d * 32 + e];
  Whh[(long)row * 256 + t] = acc;
  if (t < 16) {
    int hh = t & 7;
    const float* w = attn_w + (t < 8 ? 0 : 32);
    float s = 0.f;
    for (int d = 0; d < 32; ++d) s += a[hh * 32 + d] * w[d];
    (t < 8 ? si : sj)[(long)row * 8 + hh] = s;
  }
}

// ---------------- pass A: se[b,i,j,h] = edge . V_h + ch ----------------
__global__ __launch_bounds__(256) void se_kernel(const float* edge, const float* Vg,
                                                 const float* chg, float* se) {
  int t = threadIdx.x;
  int l16 = t & 15;
  long gid = ((long)blockIdx.x * 256 + t) >> 4;
  long ngroups = ((long)gridDim.x * 256) >> 4;
  float vreg[8][8];
#pragma unroll
  for (int ci = 0; ci < 8; ++ci) {
    int c = (ci < 4) ? (l16 * 4 + ci) : (64 + l16 * 4 + (ci - 4));
#pragma unroll
    for (int h = 0; h < 8; ++h) vreg[ci][h] = Vg[c * 8 + h];
  }
  float chv = chg[(l16 >> 1) & 7];
  const long NR = (long)Bb * Ll * Ll;
  for (long row = gid; row < NR; row += ngroups) {
    const float4* er = reinterpret_cast<const float4*>(edge + row * 128);
    float4 e0 = er[l16];
    float4 e1 = er[16 + l16];
    float p[8];
#pragma unroll
    for (int h = 0; h < 8; ++h)
      p[h] = e0.x * vreg[0][h] + e0.y * vreg[1][h] + e0.z * vreg[2][h] + e0.w * vreg[3][h] +
             e1.x * vreg[4][h] + e1.y * vreg[5][h] + e1.z * vreg[6][h] + e1.w * vreg[7][h];
    bool hi8 = (l16 & 8) != 0;
    float q[4];
#pragma unroll
    for (int h = 0; h < 4; ++h) {
      float keep = hi8 ? p[h + 4] : p[h];
      float send = hi8 ? p[h] : p[h + 4];
      q[h] = keep + __shfl_xor(send, 8);
    }
    bool hi4 = (l16 & 4) != 0;
    float r2[2];
#pragma unroll
    for (int h = 0; h < 2; ++h) {
      float keep = hi4 ? q[h + 2] : q[h];
      float send = hi4 ? q[h] : q[h + 2];
      r2[h] = keep + __shfl_xor(send, 4);
    }
    bool hi2 = (l16 & 2) != 0;
    float s = (hi2 ? r2[1] : r2[0]) + __shfl_xor(hi2 ? r2[0] : r2[1], 2);
    s += __shfl_xor(s, 1);
    s += chv;
    if ((l16 & 1) == 0) se[row * 8 + ((l16 >> 1) & 7)] = s;
  }
}

// ---------------- softmax + aggregation + node_h ----------------
__global__ __launch_bounds__(256) void attn_agg_kernel(const float* node_p, const float* Whh,
                                                       const float* si, const float* sj,
                                                       const float* se, float* node_h) {
  __shared__ float sjl[2048];
  __shared__ float sel[2048];
  __shared__ float pl[2048];
  __shared__ float sil[8];
  int t = threadIdx.x;
  int bi = blockIdx.x;
  int b = bi >> 8, i = bi & 255;
  for (int q = t; q < 2048; q += 256) sjl[q] = sj[(long)b * 2048 + q];
  for (int q = t; q < 2048; q += 256) sel[q] = se[(long)bi * 2048 + q];
  if (t < 8) sil[t] = si[(long)bi * 8 + t];
  __syncthreads();
  int g = t >> 5, l32 = t & 31;
  float sc[8];
  float mx = -1e30f;
#pragma unroll
  for (int m = 0; m < 8; ++m) {
    int k = l32 + 32 * m;
    float v = -1e30f;
    if (k < 255) {
      int jj = k + (k >= i ? 1 : 0);
      v = sil[g] + sjl[jj * 8 + g] + sel[jj * 8 + g];
      v = lrelu(v);
    }
    sc[m] = v;
    mx = fmaxf(mx, v);
  }
#pragma unroll
  for (int d = 16; d >= 1; d >>= 1) mx = fmaxf(mx, __shfl_xor(mx, d));
  float sum = 0.f;
#pragma unroll
  for (int m = 0; m < 8; ++m) {
    int k = l32 + 32 * m;
    float e = (k < 255) ? __expf(sc[m] - mx) : 0.f;
    sc[m] = e;
    sum += e;
  }
#pragma unroll
  for (int d = 16; d >= 1; d >>= 1) sum += __shfl_xor(sum, d);
  float inv = 1.f / sum;
#pragma unroll
  for (int m = 0; m < 8; ++m) {
    int k = l32 + 32 * m;
    if (k < 255) pl[k * 8 + g] = sc[m] * inv;
  }
  __syncthreads();
  int h = g, e = l32;
  float acc = 0.f;
  for (int j = 0; j < 256; ++j) {
    if (j == i) continue;
    int k = (j + 254) % 255; // (j-1) mod 255
    float w = pl[k * 8 + h];
    acc += w * Whh[((long)b * 256 + j) * 256 + h * 32 + e];
  }
  float np = node_p[(long)bi * 256 + t];
  node_h[(long)bi * 256 + t] = np + lrelu(acc);
}

// ---------------- NI/NJ -> P/Q ----------------
__global__ __launch_bounds__(256) void pq_kernel(const float* node_p2, const float* edge_w,
                                                 const float* out_e_w, float* Pg, float* Qg) {
  __shared__ float a[256];
  __shared__ float NI[128], NJ[128];
  int row = blockIdx.x, t = threadIdx.x;
  a[t] = node_p2[(long)row * 256 + t];
  __syncthreads();
  {
    int f = t & 127, h = f >> 4, e = f & 15;
    const float* w = (t < 128) ? (edge_w + 256) : (edge_w + 768); // w_i / w_j
    float s = 0.f;
    for (int d = 0; d < 32; ++d) s += a[h * 32 + d] * w[d * 16 + e];
    (t < 128 ? NI : NJ)[f] = s;
  }
  __syncthreads();
  int o = t & 127;
  const float* src = (t < 128) ? NI : NJ;
  float s = 0.f;
  for (int f = 0; f < 128; ++f) s += src[f] * out_e_w[f * 128 + o];
  ((t < 128) ? Pg : Qg)[(long)row * 128 + o] = s;
}

// ---------------- pass C: new_edge = edge@G + P_i + Q_j + c0 (diag: out_e_b) ----------------
__global__ __launch_bounds__(256) void edge_out_kernel(const float* edge, const float* Gg,
                                                       const float* Pg, const float* Qg,
                                                       const float* c0g, const float* oeb,
                                                       float* out_edge) {
  __shared__ float Gl[128 * 128];
  __shared__ float et[64 * 129];
  __shared__ float Pl[128];
  __shared__ float c0l[128];
  __shared__ float oebl[128];
  int t = threadIdx.x;
  for (int q = t; q < 4096; q += 256)
    reinterpret_cast<float4*>(Gl)[q] = reinterpret_cast<const float4*>(Gg)[q];
  long row0 = (long)blockIdx.x * 64;
  int b = (int)(row0 >> 16);
  int i = (int)((row0 >> 8) & 255);
  int j0 = (int)(row0 & 255);
  if (t < 128) {
    Pl[t] = Pg[((long)(b * 256 + i)) * 128 + t];
    c0l[t] = c0g[t];
    oebl[t] = oeb[t];
  }
  for (int q = t; q < 2048; q += 256) {
    int row = q >> 5, c4 = q & 31;
    float4 v = reinterpret_cast<const float4*>(edge)[row0 * 32 + q];
    int base = row * 129 + c4 * 4;
    et[base] = v.x;
    et[base + 1] = v.y;
    et[base + 2] = v.z;
    et[base + 3] = v.w;
  }
  __syncthreads();
  int tr = t >> 4, tc = t & 15;
  float acc[4][8];
#pragma unroll
  for (int r = 0; r < 4; ++r)
#pragma unroll
    for (int k = 0; k < 8; ++k) acc[r][k] = 0.f;
#pragma unroll 2
  for (int c = 0; c < 128; ++c) {
    float aa[4];
#pragma unroll
    for (int r = 0; r < 4; ++r) aa[r] = et[(tr * 4 + r) * 129 + c];
    float4 b0 = *reinterpret_cast<const float4*>(&Gl[c * 128 + tc * 8]);
    float4 b1 = *reinterpret_cast<const float4*>(&Gl[c * 128 + tc * 8 + 4]);
    float bb[8] = {b0.x, b0.y, b0.z, b0.w, b1.x, b1.y, b1.z, b1.w};
#pragma unroll
    for (int r = 0; r < 4; ++r)
#pragma unroll
      for (int k = 0; k < 8; ++k) acc[r][k] += aa[r] * bb[k];
  }
#pragma unroll
  for (int r = 0; r < 4; ++r) {
    int row = tr * 4 + r;
    int j = j0 + row;
    long orow = (row0 + row) * 128;
    const float* Qrow = Qg + ((long)(b * 256 + j)) * 128;
    if (i == j) {
#pragma unroll
      for (int k = 0; k < 8; ++k) out_edge[orow + tc * 8 + k] = oebl[tc * 8 + k];
    } else {
#pragma unroll
      for (int k = 0; k < 8; ++k) {
        int o = tc * 8 + k;
        out_edge[orow + o] = acc[r][k] + Pl[o] + Qrow[o] + c0l[o];
      }
    }
  }
}

extern "C" void kernel_launch(void* const* d_in, const int* in_sizes, int n_in,
                              void* d_out, int out_size, void* d_ws, size_t ws_size,
                              hipStream_t stream) {
  const float* node = (const float*)d_in[0];
  const float* edge = (const float*)d_in[1];
  const float* Wn_w = (const float*)d_in[2];
  const float* Wn_b = (const float*)d_in[3];
  const float* Wh_w = (const float*)d_in[4];
  const float* Wh_b = (const float*)d_in[5];
  const float* We_w = (const float*)d_in[6];
  const float* We_b = (const float*)d_in[7];
  const float* Wn2_w = (const float*)d_in[8];
  const float* Wn2_b = (const float*)d_in[9];
  const float* We2_w = (const float*)d_in[10];
  const float* We2_b = (const float*)d_in[11];
  const float* attn_w = (const float*)d_in[12];
  const float* edge_w = (const float*)d_in[13];
  const float* edge_b = (const float*)d_in[14];
  const float* out_n_w = (const float*)d_in[15];
  const float* out_n_b = (const float*)d_in[16];
  const float* out_e_w = (const float*)d_in[17];
  const float* out_e_b = (const float*)d_in[18];

  float* out_node = (float*)d_out;                 // 262144
  float* out_edge = ((float*)d_out) + 262144;      // 33554432

  float* ws = (float*)d_ws;
  float* node_p  = ws;                // 262144
  float* Whh     = ws + 262144;       // 262144
  float* node_h  = ws + 524288;       // 262144
  float* node_p2 = ws + 786432;       // 262144
  float* si      = ws + 1048576;      // 8192
  float* sjv     = ws + 1056768;      // 8192
  float* Pg      = ws + 1064960;      // 131072
  float* Qg      = ws + 1196032;      // 131072
  float* Vg      = ws + 1327104;      // 1024
  float* chg     = ws + 1328128;      // 8 (pad to 128)
  float* Gg      = ws + 1328256;      // 16384
  float* c0g     = ws + 1344640;      // 128
  float* seg     = ws + 1344768;      // 2097152

  prep_small<<<1, 128, 0, stream>>>(We_w, We_b, attn_w, We2_b, edge_w, edge_b, out_e_w,
                                    out_e_b, Vg, chg, c0g);
  prep_g<<<128, 128, 0, stream>>>(We2_w, edge_w, out_e_w, Gg);
  rowgemm256<4><<<256, 256, 0, stream>>>(node, Wn_w, Wn_b, node_p);
  node_heads_kernel<<<1024, 256, 0, stream>>>(node_p, Wh_w, Wh_b, attn_w, Whh, si, sjv);
  se_kernel<<<2048, 256, 0, stream>>>(edge, Vg, chg, seg);
  attn_agg_kernel<<<1024, 256, 0, stream>>>(node_p, Whh, si, sjv, seg, node_h);
  rowgemm256<4><<<256, 256, 0, stream>>>(node_h, out_n_w, out_n_b, out_node);
  rowgemm256<4><<<256, 256, 0, stream>>>(out_node, Wn2_w, Wn2_b, node_p2);
  pq_kernel<<<1024, 256, 0, stream>>>(node_p2, edge_w, out_e_w, Pg, Qg);
  edge_out_kernel<<<4096, 256, 0, stream>>>(edge, Gg, Pg, Qg, c0g, out_e_b, out_edge);
}

// Round 2
// 258.393 us; speedup vs baseline: 1.8758x; 1.8758x over previous
//
#include <hip/hip_runtime.h>

#define Bb 4
#define Ll 256
#define NEG 0.2f

typedef __attribute__((ext_vector_type(8))) short short8;
typedef __attribute__((ext_vector_type(4))) short short4v;
typedef __attribute__((ext_vector_type(4))) float f32x4;

__device__ __forceinline__ float lrelu(float x) { return x >= 0.f ? x : NEG * x; }

__device__ __forceinline__ short f2bf(float x) {
  unsigned u = __builtin_bit_cast(unsigned, x);
  unsigned r = (u + 0x7FFFu + ((u >> 16) & 1u)) >> 16;
  return (short)r;
}

// ---------------- prep: V (128x8), ch(8), c0(128) ----------------
__global__ void prep_small(const float* We_w, const float* We_b, const float* attn_w,
                           const float* We2_b, const float* edge_w, const float* edge_b,
                           const float* out_e_w, const float* out_e_b,
                           float* Vg, float* chg, float* c0g) {
  __shared__ float b2e[128];
  int t = threadIdx.x; // 128 threads
  const float* we = attn_w + 64;
  for (int idx = t; idx < 1024; idx += 128) {
    int c = idx >> 3, h = idx & 7;
    float s = 0.f;
    for (int d = 0; d < 16; ++d) s += We_w[c * 128 + h * 16 + d] * we[d];
    Vg[idx] = s; // V[c*8+h]
  }
  if (t < 8) {
    float s = 0.f;
    for (int d = 0; d < 16; ++d) s += We_b[t * 16 + d] * we[d];
    chg[t] = s;
  }
  {
    int h = t >> 4, e = t & 15;
    float s = 0.f;
    for (int d = 0; d < 16; ++d) s += We2_b[h * 16 + d] * edge_w[d * 16 + e];
    b2e[t] = s + edge_b[e];
  }
  __syncthreads();
  float s = out_e_b[t];
  for (int f = 0; f < 128; ++f) s += b2e[f] * out_e_w[f * 128 + t];
  c0g[t] = s;
}

// ---------------- prep: G = M2 @ out_e_w (128x128), stored as bf16 swizzled
// LDS image of Gt[n][k]: byte(n,k) = n*256 + ((2k) ^ ((n&7)<<4)) ----------------
__global__ void prep_g(const float* We2_w, const float* edge_w, const float* out_e_w,
                       short* Gsw) {
  __shared__ float m2[128];
  int c = blockIdx.x, t = threadIdx.x; // c = input channel (K index), t = output channel (n)
  int h = t >> 4, e = t & 15;
  float s = 0.f;
  for (int d = 0; d < 16; ++d) s += We2_w[c * 128 + h * 16 + d] * edge_w[d * 16 + e];
  m2[t] = s;
  __syncthreads();
  float g = 0.f;
  for (int f = 0; f < 128; ++f) g += m2[f] * out_e_w[f * 128 + t];
  int off = t * 256 + ((2 * c) ^ ((t & 7) << 4));
  *(short*)((char*)Gsw + off) = f2bf(g);
}

// ---------------- generic 256->256 row GEMM: out = A@W + b ----------------
template <int RPB>
__global__ __launch_bounds__(256) void rowgemm256(const float* A, const float* W,
                                                  const float* bias, float* out) {
  __shared__ float a[RPB][256];
  int t = threadIdx.x;
  int row0 = blockIdx.x * RPB;
  for (int q = t; q < RPB * 256; q += 256) a[q >> 8][q & 255] = A[(long)row0 * 256 + q];
  __syncthreads();
  float acc[RPB];
  float bv = bias[t];
#pragma unroll
  for (int r = 0; r < RPB; ++r) acc[r] = bv;
  for (int k = 0; k < 256; ++k) {
    float w = W[k * 256 + t];
#pragma unroll
    for (int r = 0; r < RPB; ++r) acc[r] += a[r][k] * w;
  }
#pragma unroll
  for (int r = 0; r < RPB; ++r) out[(long)(row0 + r) * 256 + t] = acc[r];
}

// ---------------- per-row head projections: Whh, si, sj ----------------
__global__ __launch_bounds__(256) void node_heads_kernel(const float* node_p, const float* Wh_w,
                                                         const float* Wh_b, const float* attn_w,
                                                         float* Whh, float* si, float* sj) {
  __shared__ float a[256];
  int row = blockIdx.x, t = threadIdx.x;
  a[t] = node_p[(long)row * 256 + t];
  __syncthreads();
  int h = t >> 5, e = t & 31;
  float acc = Wh_b[e];
  for (int d = 0; d < 32; ++d) acc += a[h * 32 + d] * Wh_w[d * 32 + e];
  Whh[(long)row * 256 + t] = acc;
  if (t < 16) {
    int hh = t & 7;
    const float* w = attn_w + (t < 8 ? 0 : 32);
    float s = 0.f;
    for (int d = 0; d < 32; ++d) s += a[hh * 32 + d] * w[d];
    (t < 8 ? si : sj)[(long)row * 8 + hh] = s;
  }
}

// ---------------- pass A: se[b,i,j,h] = edge . V_h + ch ----------------
__global__ __launch_bounds__(256) void se_kernel(const float* edge, const float* Vg,
                                                 const float* chg, float* se) {
  int t = threadIdx.x;
  int l16 = t & 15;
  long gid = ((long)blockIdx.x * 256 + t) >> 4;
  long ngroups = ((long)gridDim.x * 256) >> 4;
  float vreg[8][8];
#pragma unroll
  for (int ci = 0; ci < 8; ++ci) {
    int c = (ci < 4) ? (l16 * 4 + ci) : (64 + l16 * 4 + (ci - 4));
#pragma unroll
    for (int h = 0; h < 8; ++h) vreg[ci][h] = Vg[c * 8 + h];
  }
  float chv = chg[(l16 >> 1) & 7];
  const long NR = (long)Bb * Ll * Ll;
  for (long row = gid; row < NR; row += ngroups) {
    const float4* er = reinterpret_cast<const float4*>(edge + row * 128);
    float4 e0 = er[l16];
    float4 e1 = er[16 + l16];
    float p[8];
#pragma unroll
    for (int h = 0; h < 8; ++h)
      p[h] = e0.x * vreg[0][h] + e0.y * vreg[1][h] + e0.z * vreg[2][h] + e0.w * vreg[3][h] +
             e1.x * vreg[4][h] + e1.y * vreg[5][h] + e1.z * vreg[6][h] + e1.w * vreg[7][h];
    bool hi8 = (l16 & 8) != 0;
    float q[4];
#pragma unroll
    for (int h = 0; h < 4; ++h) {
      float keep = hi8 ? p[h + 4] : p[h];
      float send = hi8 ? p[h] : p[h + 4];
      q[h] = keep + __shfl_xor(send, 8);
    }
    bool hi4 = (l16 & 4) != 0;
    float r2[2];
#pragma unroll
    for (int h = 0; h < 2; ++h) {
      float keep = hi4 ? q[h + 2] : q[h];
      float send = hi4 ? q[h] : q[h + 2];
      r2[h] = keep + __shfl_xor(send, 4);
    }
    bool hi2 = (l16 & 2) != 0;
    float s = (hi2 ? r2[1] : r2[0]) + __shfl_xor(hi2 ? r2[0] : r2[1], 2);
    s += __shfl_xor(s, 1);
    s += chv;
    if ((l16 & 1) == 0) se[row * 8 + ((l16 >> 1) & 7)] = s;
  }
}

// ---------------- softmax + aggregation + node_h ----------------
__global__ __launch_bounds__(256) void attn_agg_kernel(const float* node_p, const float* Whh,
                                                       const float* si, const float* sj,
                                                       const float* se, float* node_h) {
  __shared__ float sjl[2048];
  __shared__ float sel[2048];
  __shared__ float pl[2048];
  __shared__ float sil[8];
  int t = threadIdx.x;
  int bi = blockIdx.x;
  int b = bi >> 8, i = bi & 255;
  for (int q = t; q < 2048; q += 256) sjl[q] = sj[(long)b * 2048 + q];
  for (int q = t; q < 2048; q += 256) sel[q] = se[(long)bi * 2048 + q];
  if (t < 8) sil[t] = si[(long)bi * 8 + t];
  __syncthreads();
  int g = t >> 5, l32 = t & 31;
  float sc[8];
  float mx = -1e30f;
#pragma unroll
  for (int m = 0; m < 8; ++m) {
    int k = l32 + 32 * m;
    float v = -1e30f;
    if (k < 255) {
      int jj = k + (k >= i ? 1 : 0);
      v = sil[g] + sjl[jj * 8 + g] + sel[jj * 8 + g];
      v = lrelu(v);
    }
    sc[m] = v;
    mx = fmaxf(mx, v);
  }
#pragma unroll
  for (int d = 16; d >= 1; d >>= 1) mx = fmaxf(mx, __shfl_xor(mx, d));
  float sum = 0.f;
#pragma unroll
  for (int m = 0; m < 8; ++m) {
    int k = l32 + 32 * m;
    float e = (k < 255) ? __expf(sc[m] - mx) : 0.f;
    sc[m] = e;
    sum += e;
  }
#pragma unroll
  for (int d = 16; d >= 1; d >>= 1) sum += __shfl_xor(sum, d);
  float inv = 1.f / sum;
#pragma unroll
  for (int m = 0; m < 8; ++m) {
    int k = l32 + 32 * m;
    if (k < 255) pl[k * 8 + g] = sc[m] * inv;
  }
  __syncthreads();
  int h = g, e = l32;
  float acc = 0.f;
  for (int j = 0; j < 256; ++j) {
    if (j == i) continue;
    int k = (j + 254) % 255; // (j-1) mod 255
    float w = pl[k * 8 + h];
    acc += w * Whh[((long)b * 256 + j) * 256 + h * 32 + e];
  }
  float np = node_p[(long)bi * 256 + t];
  node_h[(long)bi * 256 + t] = np + lrelu(acc);
}

// ---------------- NI/NJ -> P/Q ----------------
__global__ __launch_bounds__(256) void pq_kernel(const float* node_p2, const float* edge_w,
                                                 const float* out_e_w, float* Pg, float* Qg) {
  __shared__ float a[256];
  __shared__ float NI[128], NJ[128];
  int row = blockIdx.x, t = threadIdx.x;
  a[t] = node_p2[(long)row * 256 + t];
  __syncthreads();
  {
    int f = t & 127, h = f >> 4, e = f & 15;
    const float* w = (t < 128) ? (edge_w + 256) : (edge_w + 768); // w_i / w_j
    float s = 0.f;
    for (int d = 0; d < 32; ++d) s += a[h * 32 + d] * w[d * 16 + e];
    (t < 128 ? NI : NJ)[f] = s;
  }
  __syncthreads();
  int o = t & 127;
  const float* src = (t < 128) ? NI : NJ;
  float s = 0.f;
  for (int f = 0; f < 128; ++f) s += src[f] * out_e_w[f * 128 + o];
  ((t < 128) ? Pg : Qg)[(long)row * 128 + o] = s;
}

// ---------------- pass C (MFMA): new_edge = edge@G + P_i + Q_j + c0 (diag: out_e_b)
// tile: 128 rows x 128 cols per block; 4 waves, each 64x64 via mfma_f32_16x16x32_bf16
__global__ __launch_bounds__(256, 2) void edge_out_kernel(const float* edge, const short* Gsw,
                                                          const float* Pg, const float* Qg,
                                                          const float* c0g, const float* oeb,
                                                          float* out_edge) {
  __shared__ short etl[128 * 128];  // bf16 A-tile, XOR-swizzled rows (pitch 256 B)
  __shared__ short gtl[128 * 128];  // bf16 Gt image (already swizzled in global)
  __shared__ float PCl[128];        // P_i + c0
  __shared__ float oebl[128];
  char* etb = (char*)etl;
  char* gtb = (char*)gtl;

  int t = threadIdx.x;
  long row0 = (long)blockIdx.x * 128;
  int b = (int)(row0 >> 16);
  int i = (int)((row0 >> 8) & 255);
  int j0 = (int)(row0 & 255);

  // stage A: 128 rows x 128 fp32 -> bf16 swizzled LDS
  const float4* esrc = reinterpret_cast<const float4*>(edge + row0 * 128);
#pragma unroll
  for (int q = 0; q < 16; ++q) {
    float4 v = esrc[q * 256 + t];
    int f = (q * 256 + t) * 4;
    int row = f >> 7, col = f & 127;
    short4v s4;
    s4.x = f2bf(v.x);
    s4.y = f2bf(v.y);
    s4.z = f2bf(v.z);
    s4.w = f2bf(v.w);
    *(short4v*)(etb + row * 256 + ((col * 2) ^ ((row & 7) << 4))) = s4;
  }
  // stage G: linear 32 KB copy of the pre-swizzled image
  {
    const uint4* gsrc = reinterpret_cast<const uint4*>(Gsw);
    uint4* gdst = reinterpret_cast<uint4*>(gtl);
#pragma unroll
    for (int q = 0; q < 8; ++q) gdst[q * 256 + t] = gsrc[q * 256 + t];
  }
  if (t < 128) {
    PCl[t] = Pg[((long)(b * 256 + i)) * 128 + t] + c0g[t];
    oebl[t] = oeb[t];
  }
  __syncthreads();

  int l = t & 63, wid = t >> 6;
  int wm = wid >> 1, wn = wid & 1; // wave computes rows [wm*64,+64), cols [wn*64,+64)
  int lc = l & 15;
  int kq = (l >> 4) << 4; // byte offset of this lane's 16B k-chunk within a k-step

  f32x4 acc[4][4];
#pragma unroll
  for (int mf = 0; mf < 4; ++mf)
#pragma unroll
    for (int nf = 0; nf < 4; ++nf) acc[mf][nf] = (f32x4){0.f, 0.f, 0.f, 0.f};

#pragma unroll
  for (int ks = 0; ks < 4; ++ks) {
    int kb = ks * 64 + kq;
    short8 av[4], bv[4];
#pragma unroll
    for (int mf = 0; mf < 4; ++mf) {
      int row = wm * 64 + mf * 16 + lc;
      av[mf] = *(const short8*)(etb + row * 256 + (kb ^ ((row & 7) << 4)));
    }
#pragma unroll
    for (int nf = 0; nf < 4; ++nf) {
      int col = wn * 64 + nf * 16 + lc;
      bv[nf] = *(const short8*)(gtb + col * 256 + (kb ^ ((col & 7) << 4)));
    }
#pragma unroll
    for (int mf = 0; mf < 4; ++mf)
#pragma unroll
      for (int nf = 0; nf < 4; ++nf)
        acc[mf][nf] = __builtin_amdgcn_mfma_f32_16x16x32_bf16(av[mf], bv[nf], acc[mf][nf], 0, 0, 0);
  }

  int lr4 = (l >> 4) * 4;
#pragma unroll
  for (int mf = 0; mf < 4; ++mf) {
#pragma unroll
    for (int r = 0; r < 4; ++r) {
      int rit = wm * 64 + mf * 16 + lr4 + r;
      int j = j0 + rit;
      bool diag = (j == i);
      const float* Qrow = Qg + ((long)(b * 256 + j)) * 128;
      float* orow = out_edge + (row0 + rit) * 128;
#pragma unroll
      for (int nf = 0; nf < 4; ++nf) {
        int col = wn * 64 + nf * 16 + lc;
        float v = diag ? oebl[col] : (acc[mf][nf][r] + PCl[col] + Qrow[col]);
        orow[col] = v;
      }
    }
  }
}

extern "C" void kernel_launch(void* const* d_in, const int* in_sizes, int n_in,
                              void* d_out, int out_size, void* d_ws, size_t ws_size,
                              hipStream_t stream) {
  const float* node = (const float*)d_in[0];
  const float* edge = (const float*)d_in[1];
  const float* Wn_w = (const float*)d_in[2];
  const float* Wn_b = (const float*)d_in[3];
  const float* Wh_w = (const float*)d_in[4];
  const float* Wh_b = (const float*)d_in[5];
  const float* We_w = (const float*)d_in[6];
  const float* We_b = (const float*)d_in[7];
  const float* Wn2_w = (const float*)d_in[8];
  const float* Wn2_b = (const float*)d_in[9];
  const float* We2_w = (const float*)d_in[10];
  const float* We2_b = (const float*)d_in[11];
  const float* attn_w = (const float*)d_in[12];
  const float* edge_w = (const float*)d_in[13];
  const float* edge_b = (const float*)d_in[14];
  const float* out_n_w = (const float*)d_in[15];
  const float* out_n_b = (const float*)d_in[16];
  const float* out_e_w = (const float*)d_in[17];
  const float* out_e_b = (const float*)d_in[18];

  float* out_node = (float*)d_out;                 // 262144
  float* out_edge = ((float*)d_out) + 262144;      // 33554432

  float* ws = (float*)d_ws;
  float* node_p  = ws;                // 262144
  float* Whh     = ws + 262144;       // 262144
  float* node_h  = ws + 524288;       // 262144
  float* node_p2 = ws + 786432;       // 262144
  float* si      = ws + 1048576;      // 8192
  float* sjv     = ws + 1056768;      // 8192
  float* Pg      = ws + 1064960;      // 131072
  float* Qg      = ws + 1196032;      // 131072
  float* Vg      = ws + 1327104;      // 1024
  float* chg     = ws + 1328128;      // 8 (pad to 128)
  short* Gsw     = (short*)(ws + 1328256); // 16384 shorts = 32 KB (in old Gg slot, 64 KB)
  float* c0g     = ws + 1344640;      // 128
  float* seg     = ws + 1344768;      // 2097152

  prep_small<<<1, 128, 0, stream>>>(We_w, We_b, attn_w, We2_b, edge_w, edge_b, out_e_w,
                                    out_e_b, Vg, chg, c0g);
  prep_g<<<128, 128, 0, stream>>>(We2_w, edge_w, out_e_w, Gsw);
  rowgemm256<4><<<256, 256, 0, stream>>>(node, Wn_w, Wn_b, node_p);
  node_heads_kernel<<<1024, 256, 0, stream>>>(node_p, Wh_w, Wh_b, attn_w, Whh, si, sjv);
  se_kernel<<<2048, 256, 0, stream>>>(edge, Vg, chg, seg);
  attn_agg_kernel<<<1024, 256, 0, stream>>>(node_p, Whh, si, sjv, seg, node_h);
  rowgemm256<4><<<256, 256, 0, stream>>>(node_h, out_n_w, out_n_b, out_node);
  rowgemm256<4><<<256, 256, 0, stream>>>(out_node, Wn2_w, Wn2_b, node_p2);
  pq_kernel<<<1024, 256, 0, stream>>>(node_p2, edge_w, out_e_w, Pg, Qg);
  edge_out_kernel<<<2048, 256, 0, stream>>>(edge, Gsw, Pg, Qg, c0g, out_e_b, out_edge);
}

// Round 3
// 257.001 us; speedup vs baseline: 1.8859x; 1.0054x over previous
//
#include <hip/hip_runtime.h>

#define Bb 4
#define Ll 256
#define NEG 0.2f

typedef __attribute__((ext_vector_type(8))) short short8;
typedef __attribute__((ext_vector_type(4))) short short4v;
typedef __attribute__((ext_vector_type(4))) float f32x4;

__device__ __forceinline__ float lrelu(float x) { return x >= 0.f ? x : NEG * x; }

__device__ __forceinline__ short f2bf(float x) {
  unsigned u = __builtin_bit_cast(unsigned, x);
  unsigned r = (u + 0x7FFFu + ((u >> 16) & 1u)) >> 16;
  return (short)r;
}

// ---------------- merged prep: blocks 0..127 -> Gt (linear bf16 [n][k]);
// block 128 -> V (128x8), ch(8), c0(128) ----------------
__global__ void prep_kernel(const float* We_w, const float* We_b, const float* attn_w,
                            const float* We2_w, const float* We2_b, const float* edge_w,
                            const float* edge_b, const float* out_e_w, const float* out_e_b,
                            float* Vg, float* chg, float* c0g, short* Gt) {
  int blk = blockIdx.x;
  int t = threadIdx.x; // 128 threads
  if (blk < 128) {
    // Gt[n][k] = G[k][n],  G = M2 @ out_e_w,  M2[k][f] from We2_w & edge_w
    __shared__ float m2[128];
    int c = blk; // k index
    int h = t >> 4, e = t & 15;
    float s = 0.f;
    for (int d = 0; d < 16; ++d) s += We2_w[c * 128 + h * 16 + d] * edge_w[d * 16 + e];
    m2[t] = s;
    __syncthreads();
    float g = 0.f;
    for (int f = 0; f < 128; ++f) g += m2[f] * out_e_w[f * 128 + t];
    Gt[t * 128 + c] = f2bf(g);
  } else {
    __shared__ float b2e[128];
    const float* we = attn_w + 64;
    for (int idx = t; idx < 1024; idx += 128) {
      int c = idx >> 3, h = idx & 7;
      float s = 0.f;
      for (int d = 0; d < 16; ++d) s += We_w[c * 128 + h * 16 + d] * we[d];
      Vg[idx] = s; // V[c*8+h]
    }
    if (t < 8) {
      float s = 0.f;
      for (int d = 0; d < 16; ++d) s += We_b[t * 16 + d] * we[d];
      chg[t] = s;
    }
    {
      int h = t >> 4, e = t & 15;
      float s = 0.f;
      for (int d = 0; d < 16; ++d) s += We2_b[h * 16 + d] * edge_w[d * 16 + e];
      b2e[t] = s + edge_b[e];
    }
    __syncthreads();
    float s = out_e_b[t];
    for (int f = 0; f < 128; ++f) s += b2e[f] * out_e_w[f * 128 + t];
    c0g[t] = s;
  }
}

// ---------------- generic 256->256 row GEMM: out = A@W + b ----------------
template <int RPB>
__global__ __launch_bounds__(256) void rowgemm256(const float* A, const float* W,
                                                  const float* bias, float* out) {
  __shared__ float a[RPB][256];
  int t = threadIdx.x;
  int row0 = blockIdx.x * RPB;
  for (int q = t; q < RPB * 256; q += 256) a[q >> 8][q & 255] = A[(long)row0 * 256 + q];
  __syncthreads();
  float acc[RPB];
  float bv = bias[t];
#pragma unroll
  for (int r = 0; r < RPB; ++r) acc[r] = bv;
  for (int k = 0; k < 256; ++k) {
    float w = W[k * 256 + t];
#pragma unroll
    for (int r = 0; r < RPB; ++r) acc[r] += a[r][k] * w;
  }
#pragma unroll
  for (int r = 0; r < RPB; ++r) out[(long)(row0 + r) * 256 + t] = acc[r];
}

// ---------------- per-row head projections: Whh, si, sj ----------------
__global__ __launch_bounds__(256) void node_heads_kernel(const float* node_p, const float* Wh_w,
                                                         const float* Wh_b, const float* attn_w,
                                                         float* Whh, float* si, float* sj) {
  __shared__ float a[256];
  int row = blockIdx.x, t = threadIdx.x;
  a[t] = node_p[(long)row * 256 + t];
  __syncthreads();
  int h = t >> 5, e = t & 31;
  float acc = Wh_b[e];
  for (int d = 0; d < 32; ++d) acc += a[h * 32 + d] * Wh_w[d * 32 + e];
  Whh[(long)row * 256 + t] = acc;
  if (t < 16) {
    int hh = t & 7;
    const float* w = attn_w + (t < 8 ? 0 : 32);
    float s = 0.f;
    for (int d = 0; d < 32; ++d) s += a[hh * 32 + d] * w[d];
    (t < 8 ? si : sj)[(long)row * 8 + hh] = s;
  }
}

// ---------------- pass A: se[b,i,j,h] = edge . V_h + ch ----------------
__global__ __launch_bounds__(256) void se_kernel(const float* edge, const float* Vg,
                                                 const float* chg, float* se) {
  int t = threadIdx.x;
  int l16 = t & 15;
  long gid = ((long)blockIdx.x * 256 + t) >> 4;
  long ngroups = ((long)gridDim.x * 256) >> 4;
  float vreg[8][8];
#pragma unroll
  for (int ci = 0; ci < 8; ++ci) {
    int c = (ci < 4) ? (l16 * 4 + ci) : (64 + l16 * 4 + (ci - 4));
#pragma unroll
    for (int h = 0; h < 8; ++h) vreg[ci][h] = Vg[c * 8 + h];
  }
  float chv = chg[(l16 >> 1) & 7];
  const long NR = (long)Bb * Ll * Ll;
  for (long row = gid; row < NR; row += ngroups) {
    const float4* er = reinterpret_cast<const float4*>(edge + row * 128);
    float4 e0 = er[l16];
    float4 e1 = er[16 + l16];
    float p[8];
#pragma unroll
    for (int h = 0; h < 8; ++h)
      p[h] = e0.x * vreg[0][h] + e0.y * vreg[1][h] + e0.z * vreg[2][h] + e0.w * vreg[3][h] +
             e1.x * vreg[4][h] + e1.y * vreg[5][h] + e1.z * vreg[6][h] + e1.w * vreg[7][h];
    bool hi8 = (l16 & 8) != 0;
    float q[4];
#pragma unroll
    for (int h = 0; h < 4; ++h) {
      float keep = hi8 ? p[h + 4] : p[h];
      float send = hi8 ? p[h] : p[h + 4];
      q[h] = keep + __shfl_xor(send, 8);
    }
    bool hi4 = (l16 & 4) != 0;
    float r2[2];
#pragma unroll
    for (int h = 0; h < 2; ++h) {
      float keep = hi4 ? q[h + 2] : q[h];
      float send = hi4 ? q[h] : q[h + 2];
      r2[h] = keep + __shfl_xor(send, 4);
    }
    bool hi2 = (l16 & 2) != 0;
    float s = (hi2 ? r2[1] : r2[0]) + __shfl_xor(hi2 ? r2[0] : r2[1], 2);
    s += __shfl_xor(s, 1);
    s += chv;
    if ((l16 & 1) == 0) se[row * 8 + ((l16 >> 1) & 7)] = s;
  }
}

// ---------------- softmax + aggregation + node_h ----------------
__global__ __launch_bounds__(256) void attn_agg_kernel(const float* node_p, const float* Whh,
                                                       const float* si, const float* sj,
                                                       const float* se, float* node_h) {
  __shared__ float sjl[2048];
  __shared__ float sel[2048];
  __shared__ float pl[2048];
  __shared__ float sil[8];
  int t = threadIdx.x;
  int bi = blockIdx.x;
  int b = bi >> 8, i = bi & 255;
  for (int q = t; q < 2048; q += 256) sjl[q] = sj[(long)b * 2048 + q];
  for (int q = t; q < 2048; q += 256) sel[q] = se[(long)bi * 2048 + q];
  if (t < 8) sil[t] = si[(long)bi * 8 + t];
  __syncthreads();
  int g = t >> 5, l32 = t & 31;
  float sc[8];
  float mx = -1e30f;
#pragma unroll
  for (int m = 0; m < 8; ++m) {
    int k = l32 + 32 * m;
    float v = -1e30f;
    if (k < 255) {
      int jj = k + (k >= i ? 1 : 0);
      v = sil[g] + sjl[jj * 8 + g] + sel[jj * 8 + g];
      v = lrelu(v);
    }
    sc[m] = v;
    mx = fmaxf(mx, v);
  }
#pragma unroll
  for (int d = 16; d >= 1; d >>= 1) mx = fmaxf(mx, __shfl_xor(mx, d));
  float sum = 0.f;
#pragma unroll
  for (int m = 0; m < 8; ++m) {
    int k = l32 + 32 * m;
    float e = (k < 255) ? __expf(sc[m] - mx) : 0.f;
    sc[m] = e;
    sum += e;
  }
#pragma unroll
  for (int d = 16; d >= 1; d >>= 1) sum += __shfl_xor(sum, d);
  float inv = 1.f / sum;
#pragma unroll
  for (int m = 0; m < 8; ++m) {
    int k = l32 + 32 * m;
    if (k < 255) pl[k * 8 + g] = sc[m] * inv;
  }
  __syncthreads();
  int h = g, e = l32;
  float acc = 0.f;
  for (int j = 0; j < 256; ++j) {
    if (j == i) continue;
    int k = (j + 254) % 255; // (j-1) mod 255
    float w = pl[k * 8 + h];
    acc += w * Whh[((long)b * 256 + j) * 256 + h * 32 + e];
  }
  float np = node_p[(long)bi * 256 + t];
  node_h[(long)bi * 256 + t] = np + lrelu(acc);
}

// ---------------- NI/NJ -> P/Q ----------------
__global__ __launch_bounds__(256) void pq_kernel(const float* node_p2, const float* edge_w,
                                                 const float* out_e_w, float* Pg, float* Qg) {
  __shared__ float a[256];
  __shared__ float NI[128], NJ[128];
  int row = blockIdx.x, t = threadIdx.x;
  a[t] = node_p2[(long)row * 256 + t];
  __syncthreads();
  {
    int f = t & 127, h = f >> 4, e = f & 15;
    const float* w = (t < 128) ? (edge_w + 256) : (edge_w + 768); // w_i / w_j
    float s = 0.f;
    for (int d = 0; d < 32; ++d) s += a[h * 32 + d] * w[d * 16 + e];
    (t < 128 ? NI : NJ)[f] = s;
  }
  __syncthreads();
  int o = t & 127;
  const float* src = (t < 128) ? NI : NJ;
  float s = 0.f;
  for (int f = 0; f < 128; ++f) s += src[f] * out_e_w[f * 128 + o];
  ((t < 128) ? Pg : Qg)[(long)row * 128 + o] = s;
}

// ---------------- pass C (MFMA, pipelined): new_edge = edge@G + P_i + Q_j + c0
// 512 blocks x 4 tiles; tile = 128 rows x 128 cols; G in registers; dbuf LDS A.
__global__ __launch_bounds__(256, 2) void edge_out_kernel(
    const float* __restrict__ edge, const short* __restrict__ Gt,
    const float* __restrict__ Pg, const float* __restrict__ Qg,
    const float* __restrict__ c0g, const float* __restrict__ oeb,
    float* __restrict__ out_edge) {
  __shared__ short abuf[2][128 * 128]; // 2 x 32KB bf16 A-tiles, XOR-swizzled rows
  int t = threadIdx.x;
  int l = t & 63, wid = t >> 6;
  int wm = wid >> 1, wn = wid & 1;
  int lc = l & 15;
  int lq = l >> 4;

  // B fragments (Gt rows = output cols) in registers, once per block
  short8 bv[4][4];
#pragma unroll
  for (int ks = 0; ks < 4; ++ks)
#pragma unroll
    for (int nf = 0; nf < 4; ++nf) {
      int col = wn * 64 + nf * 16 + lc;
      bv[ks][nf] = *(const short8*)((const char*)Gt + col * 256 + ks * 64 + lq * 16);
    }

  const int TPB = 4;
  long tile0 = (long)blockIdx.x * TPB;

  float4 st[16];
  {
    const float4* esrc = reinterpret_cast<const float4*>(edge) + tile0 * 4096;
#pragma unroll
    for (int q = 0; q < 16; ++q) st[q] = esrc[q * 256 + t];
  }

  auto writestage = [&](int buf) {
    char* base = (char*)abuf[buf];
#pragma unroll
    for (int q = 0; q < 16; ++q) {
      int f = (q * 256 + t) * 4;
      int row = f >> 7, col = f & 127;
      short4v s4;
      s4.x = f2bf(st[q].x);
      s4.y = f2bf(st[q].y);
      s4.z = f2bf(st[q].z);
      s4.w = f2bf(st[q].w);
      *(short4v*)(base + row * 256 + ((col * 2) ^ ((row & 7) << 4))) = s4;
    }
  };
  writestage(0);

  int cur = 0;
  for (int tt = 0; tt < TPB; ++tt) {
    long tile = tile0 + tt;
    if (tt + 1 < TPB) {
      const float4* esrc = reinterpret_cast<const float4*>(edge) + (tile + 1) * 4096;
#pragma unroll
      for (int q = 0; q < 16; ++q) st[q] = esrc[q * 256 + t];
    }
    __syncthreads();

    char* etb = (char*)abuf[cur];
    f32x4 acc[4][4];
#pragma unroll
    for (int mf = 0; mf < 4; ++mf)
#pragma unroll
      for (int nf = 0; nf < 4; ++nf) acc[mf][nf] = (f32x4){0.f, 0.f, 0.f, 0.f};

#pragma unroll
    for (int ks = 0; ks < 4; ++ks) {
      short8 av[4];
#pragma unroll
      for (int mf = 0; mf < 4; ++mf) {
        int row = wm * 64 + mf * 16 + lc;
        av[mf] = *(const short8*)(etb + row * 256 + ((ks * 64 + lq * 16) ^ ((row & 7) << 4)));
      }
#pragma unroll
      for (int mf = 0; mf < 4; ++mf)
#pragma unroll
        for (int nf = 0; nf < 4; ++nf)
          acc[mf][nf] =
              __builtin_amdgcn_mfma_f32_16x16x32_bf16(bv[ks][nf], av[mf], acc[mf][nf], 0, 0, 0);
    }

    // epilogue: D[m][n]: m -> output col (4 consecutive per lane), n -> edge row
    long row0 = tile * 128;
    int b = (int)(row0 >> 16);
    int i = (int)((row0 >> 8) & 255);
    int j0 = (int)(row0 & 255);
    f32x4 pc[4];
#pragma unroll
    for (int nf = 0; nf < 4; ++nf) {
      int cb = wn * 64 + nf * 16 + lq * 4;
      f32x4 p = *(const f32x4*)(Pg + ((long)(b * 256 + i)) * 128 + cb);
      f32x4 c0 = *(const f32x4*)(c0g + cb);
      pc[nf] = p + c0;
    }
#pragma unroll
    for (int mf = 0; mf < 4; ++mf) {
      int er = wm * 64 + mf * 16 + lc;
      int j = j0 + er;
      const float* Qrow = Qg + ((long)(b * 256 + j)) * 128;
      float* orow = out_edge + (row0 + er) * 128;
      if (j == i) {
#pragma unroll
        for (int nf = 0; nf < 4; ++nf) {
          int cb = wn * 64 + nf * 16 + lq * 4;
          *(f32x4*)(orow + cb) = *(const f32x4*)(oeb + cb);
        }
      } else {
#pragma unroll
        for (int nf = 0; nf < 4; ++nf) {
          int cb = wn * 64 + nf * 16 + lq * 4;
          f32x4 q4 = *(const f32x4*)(Qrow + cb);
          *(f32x4*)(orow + cb) = acc[mf][nf] + pc[nf] + q4;
        }
      }
    }

    if (tt + 1 < TPB) writestage(cur ^ 1);
    cur ^= 1;
  }
}

extern "C" void kernel_launch(void* const* d_in, const int* in_sizes, int n_in,
                              void* d_out, int out_size, void* d_ws, size_t ws_size,
                              hipStream_t stream) {
  const float* node = (const float*)d_in[0];
  const float* edge = (const float*)d_in[1];
  const float* Wn_w = (const float*)d_in[2];
  const float* Wn_b = (const float*)d_in[3];
  const float* Wh_w = (const float*)d_in[4];
  const float* Wh_b = (const float*)d_in[5];
  const float* We_w = (const float*)d_in[6];
  const float* We_b = (const float*)d_in[7];
  const float* Wn2_w = (const float*)d_in[8];
  const float* Wn2_b = (const float*)d_in[9];
  const float* We2_w = (const float*)d_in[10];
  const float* We2_b = (const float*)d_in[11];
  const float* attn_w = (const float*)d_in[12];
  const float* edge_w = (const float*)d_in[13];
  const float* edge_b = (const float*)d_in[14];
  const float* out_n_w = (const float*)d_in[15];
  const float* out_n_b = (const float*)d_in[16];
  const float* out_e_w = (const float*)d_in[17];
  const float* out_e_b = (const float*)d_in[18];

  float* out_node = (float*)d_out;                 // 262144
  float* out_edge = ((float*)d_out) + 262144;      // 33554432

  float* ws = (float*)d_ws;
  float* node_p  = ws;                // 262144
  float* Whh     = ws + 262144;       // 262144
  float* node_h  = ws + 524288;       // 262144
  float* node_p2 = ws + 786432;       // 262144
  float* si      = ws + 1048576;      // 8192
  float* sjv     = ws + 1056768;      // 8192
  float* Pg      = ws + 1064960;      // 131072
  float* Qg      = ws + 1196032;      // 131072
  float* Vg      = ws + 1327104;      // 1024
  float* chg     = ws + 1328128;      // 8 (pad to 128)
  short* Gt      = (short*)(ws + 1328256); // 16384 shorts = 32 KB
  float* c0g     = ws + 1344640;      // 128
  float* seg     = ws + 1344768;      // 2097152

  prep_kernel<<<129, 128, 0, stream>>>(We_w, We_b, attn_w, We2_w, We2_b, edge_w, edge_b,
                                       out_e_w, out_e_b, Vg, chg, c0g, Gt);
  rowgemm256<4><<<256, 256, 0, stream>>>(node, Wn_w, Wn_b, node_p);
  node_heads_kernel<<<1024, 256, 0, stream>>>(node_p, Wh_w, Wh_b, attn_w, Whh, si, sjv);
  se_kernel<<<2048, 256, 0, stream>>>(edge, Vg, chg, seg);
  attn_agg_kernel<<<1024, 256, 0, stream>>>(node_p, Whh, si, sjv, seg, node_h);
  rowgemm256<4><<<256, 256, 0, stream>>>(node_h, out_n_w, out_n_b, out_node);
  rowgemm256<4><<<256, 256, 0, stream>>>(out_node, Wn2_w, Wn2_b, node_p2);
  pq_kernel<<<1024, 256, 0, stream>>>(node_p2, edge_w, out_e_w, Pg, Qg);
  edge_out_kernel<<<512, 256, 0, stream>>>(edge, Gt, Pg, Qg, c0g, out_e_b, out_edge);
}

// Round 4
// 173.293 us; speedup vs baseline: 2.7969x; 1.4830x over previous
//
#include <hip/hip_runtime.h>

#define Bb 4
#define Ll 256
#define NEG 0.2f

typedef __attribute__((ext_vector_type(8))) short short8;
typedef __attribute__((ext_vector_type(4))) float f32x4;
typedef __attribute__((ext_vector_type(4))) unsigned uint4v;

__device__ __forceinline__ float lrelu(float x) { return x >= 0.f ? x : NEG * x; }

__device__ __forceinline__ short f2bf(float x) {
  unsigned u = __builtin_bit_cast(unsigned, x);
  unsigned r = (u + 0x7FFFu + ((u >> 16) & 1u)) >> 16;
  return (short)r;
}

// pack two f32 -> u32 of 2 bf16 (round half up)
__device__ __forceinline__ unsigned pack2bf(float e, float o) {
  unsigned ue = __builtin_bit_cast(unsigned, e);
  unsigned uo = __builtin_bit_cast(unsigned, o);
  return ((ue + 0x8000u) >> 16) | ((uo + 0x8000u) & 0xFFFF0000u);
}

// ---------------- merged prep: blocks 0..127 -> Gt (linear bf16 [n][k]);
// block 128 -> V (128x8), ch(8), c0(128) ----------------
__global__ void prep_kernel(const float* We_w, const float* We_b, const float* attn_w,
                            const float* We2_w, const float* We2_b, const float* edge_w,
                            const float* edge_b, const float* out_e_w, const float* out_e_b,
                            float* Vg, float* chg, float* c0g, short* Gt) {
  int blk = blockIdx.x;
  int t = threadIdx.x; // 128 threads
  if (blk < 128) {
    __shared__ float m2[128];
    int c = blk; // k index
    int h = t >> 4, e = t & 15;
    float s = 0.f;
    for (int d = 0; d < 16; ++d) s += We2_w[c * 128 + h * 16 + d] * edge_w[d * 16 + e];
    m2[t] = s;
    __syncthreads();
    float g = 0.f;
    for (int f = 0; f < 128; ++f) g += m2[f] * out_e_w[f * 128 + t];
    Gt[t * 128 + c] = f2bf(g);
  } else {
    __shared__ float b2e[128];
    const float* we = attn_w + 64;
    for (int idx = t; idx < 1024; idx += 128) {
      int c = idx >> 3, h = idx & 7;
      float s = 0.f;
      for (int d = 0; d < 16; ++d) s += We_w[c * 128 + h * 16 + d] * we[d];
      Vg[idx] = s; // V[c*8+h]
    }
    if (t < 8) {
      float s = 0.f;
      for (int d = 0; d < 16; ++d) s += We_b[t * 16 + d] * we[d];
      chg[t] = s;
    }
    {
      int h = t >> 4, e = t & 15;
      float s = 0.f;
      for (int d = 0; d < 16; ++d) s += We2_b[h * 16 + d] * edge_w[d * 16 + e];
      b2e[t] = s + edge_b[e];
    }
    __syncthreads();
    float s = out_e_b[t];
    for (int f = 0; f < 128; ++f) s += b2e[f] * out_e_w[f * 128 + t];
    c0g[t] = s;
  }
}

// ---------------- node_in_fused: node_p = node@Wn + b; Whh; si; sj ----------------
__global__ __launch_bounds__(256) void node_in_fused(
    const float* __restrict__ node, const float* __restrict__ Wn_w,
    const float* __restrict__ Wn_b, const float* __restrict__ Wh_w,
    const float* __restrict__ Wh_b, const float* __restrict__ attn_w,
    float* __restrict__ node_p, float* __restrict__ Whh, float* __restrict__ si,
    float* __restrict__ sj) {
  __shared__ float a[4][256];
  __shared__ float np[4][256];
  int t = threadIdx.x;
  int row0 = blockIdx.x * 4;
  for (int q = t; q < 1024; q += 256) a[q >> 8][q & 255] = node[(long)row0 * 256 + q];
  __syncthreads();
  float acc[4];
  float bvv = Wn_b[t];
#pragma unroll
  for (int r = 0; r < 4; ++r) acc[r] = bvv;
  for (int k = 0; k < 256; ++k) {
    float w = Wn_w[k * 256 + t];
#pragma unroll
    for (int r = 0; r < 4; ++r) acc[r] += a[r][k] * w;
  }
#pragma unroll
  for (int r = 0; r < 4; ++r) {
    node_p[(long)(row0 + r) * 256 + t] = acc[r];
    np[r][t] = acc[r];
  }
  __syncthreads();
  int h = t >> 5, e = t & 31;
  float wb2 = Wh_b[e];
#pragma unroll
  for (int r = 0; r < 4; ++r) {
    float s = wb2;
    for (int d = 0; d < 32; ++d) s += np[r][h * 32 + d] * Wh_w[d * 32 + e];
    Whh[(long)(row0 + r) * 256 + t] = s;
  }
  if (t < 64) {
    int r = t >> 4, idx = t & 15, hh = idx & 7;
    const float* w = attn_w + (idx < 8 ? 0 : 32);
    float s = 0.f;
    for (int d = 0; d < 32; ++d) s += np[r][hh * 32 + d] * w[d];
    ((idx < 8) ? si : sj)[(long)(row0 + r) * 8 + hh] = s;
  }
}

// ---------------- attn_fused: per (b,i): se from edge slab -> softmax -> agg -> node_h
__global__ __launch_bounds__(256) void attn_fused(
    const float* __restrict__ node_p, const float* __restrict__ Whh,
    const float* __restrict__ si, const float* __restrict__ sj,
    const float* __restrict__ edge, const float* __restrict__ Vg,
    const float* __restrict__ chg, float* __restrict__ node_h) {
  __shared__ float sjl[2048];
  __shared__ float sel[2048];
  __shared__ float pl[2048];
  __shared__ float sil[8];
  int t = threadIdx.x, bi = blockIdx.x;
  int b = bi >> 8, i = bi & 255;
  for (int q = t; q < 2048; q += 256) sjl[q] = sj[(long)b * 2048 + q];
  if (t < 8) sil[t] = si[(long)bi * 8 + t];

  // --- se phase: 16 lanes per edge row ---
  int l16 = t & 15, grp = t >> 4;
  float vreg[8][8];
#pragma unroll
  for (int ci = 0; ci < 8; ++ci) {
    int c = (ci < 4) ? (l16 * 4 + ci) : (64 + l16 * 4 + (ci - 4));
#pragma unroll
    for (int h = 0; h < 8; ++h) vreg[ci][h] = Vg[c * 8 + h];
  }
  float chv = chg[(l16 >> 1) & 7];
  const float4* eb = reinterpret_cast<const float4*>(edge + (long)bi * 32768);
#pragma unroll 2
  for (int it = 0; it < 16; ++it) {
    int j = it * 16 + grp;
    float4 e0 = eb[j * 32 + l16];
    float4 e1 = eb[j * 32 + 16 + l16];
    float p[8];
#pragma unroll
    for (int h = 0; h < 8; ++h)
      p[h] = e0.x * vreg[0][h] + e0.y * vreg[1][h] + e0.z * vreg[2][h] + e0.w * vreg[3][h] +
             e1.x * vreg[4][h] + e1.y * vreg[5][h] + e1.z * vreg[6][h] + e1.w * vreg[7][h];
    bool hi8 = (l16 & 8) != 0;
    float q[4];
#pragma unroll
    for (int h = 0; h < 4; ++h) {
      float keep = hi8 ? p[h + 4] : p[h];
      float send = hi8 ? p[h] : p[h + 4];
      q[h] = keep + __shfl_xor(send, 8);
    }
    bool hi4 = (l16 & 4) != 0;
    float r2[2];
#pragma unroll
    for (int h = 0; h < 2; ++h) {
      float keep = hi4 ? q[h + 2] : q[h];
      float send = hi4 ? q[h] : q[h + 2];
      r2[h] = keep + __shfl_xor(send, 4);
    }
    bool hi2 = (l16 & 2) != 0;
    float s = (hi2 ? r2[1] : r2[0]) + __shfl_xor(hi2 ? r2[0] : r2[1], 2);
    s += __shfl_xor(s, 1);
    s += chv;
    if ((l16 & 1) == 0) sel[j * 8 + (l16 >> 1)] = s;
  }
  __syncthreads();

  // --- softmax ---
  int g = t >> 5, l32 = t & 31;
  float sc[8];
  float mx = -1e30f;
#pragma unroll
  for (int m = 0; m < 8; ++m) {
    int k = l32 + 32 * m;
    float v = -1e30f;
    if (k < 255) {
      int jj = k + (k >= i ? 1 : 0);
      v = sil[g] + sjl[jj * 8 + g] + sel[jj * 8 + g];
      v = lrelu(v);
    }
    sc[m] = v;
    mx = fmaxf(mx, v);
  }
#pragma unroll
  for (int d = 16; d >= 1; d >>= 1) mx = fmaxf(mx, __shfl_xor(mx, d));
  float sum = 0.f;
#pragma unroll
  for (int m = 0; m < 8; ++m) {
    int k = l32 + 32 * m;
    float e = (k < 255) ? __expf(sc[m] - mx) : 0.f;
    sc[m] = e;
    sum += e;
  }
#pragma unroll
  for (int d = 16; d >= 1; d >>= 1) sum += __shfl_xor(sum, d);
  float inv = 1.f / sum;
#pragma unroll
  for (int m = 0; m < 8; ++m) {
    int k = l32 + 32 * m;
    if (k < 255) pl[k * 8 + g] = sc[m] * inv;
  }
  __syncthreads();

  // --- agg ---
  int h = g;
  const float* wb = Whh + (long)b * 65536 + t;
  float acc0 = 0.f, acc1 = 0.f;
#pragma unroll 4
  for (int j = 0; j < 256; j += 2) {
    int k0 = (j == 0) ? 254 : (j - 1);
    int k1 = j;
    float w0 = (j == i) ? 0.f : pl[k0 * 8 + h];
    float w1 = (j + 1 == i) ? 0.f : pl[k1 * 8 + h];
    acc0 += w0 * wb[(long)j * 256];
    acc1 += w1 * wb[(long)(j + 1) * 256];
  }
  float acc = acc0 + acc1;
  float np = node_p[(long)bi * 256 + t];
  node_h[(long)bi * 256 + t] = np + lrelu(acc);
}

// ---------------- node_out_pq: out_node = node_h@out_n + b (write d_out);
// node_p2 = out_node@Wn2 + b; P/Q from node_p2 ----------------
__global__ __launch_bounds__(256) void node_out_pq(
    const float* __restrict__ node_h, const float* __restrict__ out_n_w,
    const float* __restrict__ out_n_b, const float* __restrict__ Wn2_w,
    const float* __restrict__ Wn2_b, const float* __restrict__ edge_w,
    const float* __restrict__ out_e_w, float* __restrict__ out_node,
    float* __restrict__ Pg, float* __restrict__ Qg) {
  __shared__ float a[4][256];
  __shared__ float b2[4][256];
  __shared__ float ninj[4][256];
  int t = threadIdx.x;
  int row0 = blockIdx.x * 4;
  for (int q = t; q < 1024; q += 256) a[q >> 8][q & 255] = node_h[(long)row0 * 256 + q];
  __syncthreads();
  float acc[4];
  float bv1 = out_n_b[t];
#pragma unroll
  for (int r = 0; r < 4; ++r) acc[r] = bv1;
  for (int k = 0; k < 256; ++k) {
    float w = out_n_w[k * 256 + t];
#pragma unroll
    for (int r = 0; r < 4; ++r) acc[r] += a[r][k] * w;
  }
#pragma unroll
  for (int r = 0; r < 4; ++r) {
    out_node[(long)(row0 + r) * 256 + t] = acc[r];
    b2[r][t] = acc[r];
  }
  __syncthreads();
  float acc2[4];
  float bv2 = Wn2_b[t];
#pragma unroll
  for (int r = 0; r < 4; ++r) acc2[r] = bv2;
  for (int k = 0; k < 256; ++k) {
    float w = Wn2_w[k * 256 + t];
#pragma unroll
    for (int r = 0; r < 4; ++r) acc2[r] += b2[r][k] * w;
  }
#pragma unroll
  for (int r = 0; r < 4; ++r) a[r][t] = acc2[r]; // a now holds node_p2 rows
  __syncthreads();
  {
    int f = t & 127, h = f >> 4, e = f & 15;
    const float* w = edge_w + 256 + (t >> 7) * 512; // w_i (rows 16..47) / w_j (rows 48..79)
#pragma unroll
    for (int r = 0; r < 4; ++r) {
      float s = 0.f;
      for (int d = 0; d < 32; ++d) s += a[r][h * 32 + d] * w[d * 16 + e];
      ninj[r][t] = s; // [0..127]=NI, [128..255]=NJ
    }
  }
  __syncthreads();
  {
    int o = t & 127;
    int half = (t >> 7) * 128;
#pragma unroll
    for (int r = 0; r < 4; ++r) {
      float s = 0.f;
      const float* src = ninj[r] + half;
      for (int f = 0; f < 128; ++f) s += src[f] * out_e_w[f * 128 + o];
      ((t < 128) ? Pg : Qg)[(long)(row0 + r) * 128 + o] = s;
    }
  }
}

// ---------------- pass C (MFMA, barrier-free streaming):
// new_edge = edge@G + P_i + Q_j + c0 (diag: out_e_b). 2048 blocks x 1 tile (128x128).
__global__ __launch_bounds__(256, 2) void edge_out_kernel(
    const float* __restrict__ edge, const short* __restrict__ Gt,
    const float* __restrict__ Pg, const float* __restrict__ Qg,
    const float* __restrict__ c0g, const float* __restrict__ oeb,
    float* __restrict__ out_edge) {
  int t = threadIdx.x;
  int l = t & 63, wid = t >> 6;
  int wm = wid >> 1, wn = wid & 1;
  int lc = l & 15, lq = l >> 4;

  long row0 = (long)blockIdx.x * 128;
  int b = (int)(row0 >> 16);
  int i = (int)((row0 >> 8) & 255);
  int j0 = (int)(row0 & 255);

  // B fragments: output col = wn*64+nf*16+lc, k-slice = ks*32+lq*8 (8 bf16)
  short8 bv[4][4];
#pragma unroll
  for (int ks = 0; ks < 4; ++ks)
#pragma unroll
    for (int nf = 0; nf < 4; ++nf)
      bv[ks][nf] = *(const short8*)(Gt + (wn * 64 + nf * 16 + lc) * 128 + ks * 32 + lq * 8);

  f32x4 acc[4][4];
#pragma unroll
  for (int mf = 0; mf < 4; ++mf)
#pragma unroll
    for (int nf = 0; nf < 4; ++nf) acc[mf][nf] = (f32x4){0.f, 0.f, 0.f, 0.f};

  const float* ebase = edge + row0 * 128;
#pragma unroll
  for (int ks = 0; ks < 4; ++ks) {
    short8 av[4];
#pragma unroll
    for (int mf = 0; mf < 4; ++mf) {
      const float* ap = ebase + (long)(wm * 64 + mf * 16 + lc) * 128 + ks * 32 + lq * 8;
      float4 f0 = *(const float4*)ap;
      float4 f1 = *(const float4*)(ap + 4);
      uint4v u;
      u.x = pack2bf(f0.x, f0.y);
      u.y = pack2bf(f0.z, f0.w);
      u.z = pack2bf(f1.x, f1.y);
      u.w = pack2bf(f1.z, f1.w);
      av[mf] = __builtin_bit_cast(short8, u);
    }
#pragma unroll
    for (int mf = 0; mf < 4; ++mf)
#pragma unroll
      for (int nf = 0; nf < 4; ++nf)
        acc[mf][nf] =
            __builtin_amdgcn_mfma_f32_16x16x32_bf16(bv[ks][nf], av[mf], acc[mf][nf], 0, 0, 0);
  }

  // epilogue: acc[mf][nf][r]: edge row = wm*64+mf*16+lc, col = wn*64+nf*16+lq*4+r
  f32x4 pc[4];
#pragma unroll
  for (int nf = 0; nf < 4; ++nf) {
    int cb = wn * 64 + nf * 16 + lq * 4;
    f32x4 p = *(const f32x4*)(Pg + ((long)(b * 256 + i)) * 128 + cb);
    f32x4 c0 = *(const f32x4*)(c0g + cb);
    pc[nf] = p + c0;
  }
#pragma unroll
  for (int mf = 0; mf < 4; ++mf) {
    int er = wm * 64 + mf * 16 + lc;
    int j = j0 + er;
    const float* Qrow = Qg + ((long)(b * 256 + j)) * 128;
    float* orow = out_edge + (row0 + er) * 128;
    if (j == i) {
#pragma unroll
      for (int nf = 0; nf < 4; ++nf) {
        int cb = wn * 64 + nf * 16 + lq * 4;
        *(f32x4*)(orow + cb) = *(const f32x4*)(oeb + cb);
      }
    } else {
#pragma unroll
      for (int nf = 0; nf < 4; ++nf) {
        int cb = wn * 64 + nf * 16 + lq * 4;
        f32x4 q4 = *(const f32x4*)(Qrow + cb);
        *(f32x4*)(orow + cb) = acc[mf][nf] + pc[nf] + q4;
      }
    }
  }
}

extern "C" void kernel_launch(void* const* d_in, const int* in_sizes, int n_in,
                              void* d_out, int out_size, void* d_ws, size_t ws_size,
                              hipStream_t stream) {
  const float* node = (const float*)d_in[0];
  const float* edge = (const float*)d_in[1];
  const float* Wn_w = (const float*)d_in[2];
  const float* Wn_b = (const float*)d_in[3];
  const float* Wh_w = (const float*)d_in[4];
  const float* Wh_b = (const float*)d_in[5];
  const float* We_w = (const float*)d_in[6];
  const float* We_b = (const float*)d_in[7];
  const float* Wn2_w = (const float*)d_in[8];
  const float* Wn2_b = (const float*)d_in[9];
  const float* We2_w = (const float*)d_in[10];
  const float* We2_b = (const float*)d_in[11];
  const float* attn_w = (const float*)d_in[12];
  const float* edge_w = (const float*)d_in[13];
  const float* edge_b = (const float*)d_in[14];
  const float* out_n_w = (const float*)d_in[15];
  const float* out_n_b = (const float*)d_in[16];
  const float* out_e_w = (const float*)d_in[17];
  const float* out_e_b = (const float*)d_in[18];

  float* out_node = (float*)d_out;            // 262144
  float* out_edge = ((float*)d_out) + 262144; // 33554432

  float* ws = (float*)d_ws;
  float* node_p = ws;            // 262144
  float* Whh    = ws + 262144;   // 262144
  float* node_h = ws + 524288;   // 262144
  float* si     = ws + 786432;   // 8192
  float* sjv    = ws + 794624;   // 8192
  float* Pg     = ws + 802816;   // 131072
  float* Qg     = ws + 933888;   // 131072
  float* Vg     = ws + 1064960;  // 1024
  float* chg    = ws + 1065984;  // 128 (8 used)
  short* Gt     = (short*)(ws + 1066112); // 16384 shorts = 32 KB
  float* c0g    = ws + 1074304;  // 128

  prep_kernel<<<129, 128, 0, stream>>>(We_w, We_b, attn_w, We2_w, We2_b, edge_w, edge_b,
                                       out_e_w, out_e_b, Vg, chg, c0g, Gt);
  node_in_fused<<<256, 256, 0, stream>>>(node, Wn_w, Wn_b, Wh_w, Wh_b, attn_w, node_p, Whh,
                                         si, sjv);
  attn_fused<<<1024, 256, 0, stream>>>(node_p, Whh, si, sjv, edge, Vg, chg, node_h);
  node_out_pq<<<256, 256, 0, stream>>>(node_h, out_n_w, out_n_b, Wn2_w, Wn2_b, edge_w,
                                       out_e_w, out_node, Pg, Qg);
  edge_out_kernel<<<2048, 256, 0, stream>>>(edge, Gt, Pg, Qg, c0g, out_e_b, out_edge);
}